// Round 3
// baseline (5605.721 us; speedup 1.0000x reference)
//
#include <hip/hip_runtime.h>
#include <hip/hip_bf16.h>
#include <cstdint>
#include <cstddef>

// Problem dims
#define SS   512
#define BB   64
#define EMBD 512
#define HIDD 512
#define MAXD 1024
#define NCLS 20
#define KCAT 1536
#define ROWS (SS*BB)   // 32768

// ---------- small helpers ----------
__device__ __forceinline__ uint16_t f2bf(float f) {
  uint32_t u = __float_as_uint(f);
  uint32_t r = u + 0x7fffu + ((u >> 16) & 1u);
  return (uint16_t)(r >> 16);
}
__device__ __forceinline__ float bf2f(uint32_t h) {
  return __uint_as_float(h << 16);
}
__device__ __forceinline__ uint32_t pk2(float a, float b) {
  return (uint32_t)f2bf(a) | ((uint32_t)f2bf(b) << 16);
}

#if defined(__has_builtin)
#if __has_builtin(__builtin_amdgcn_fdot2_f32_bf16)
#define USE_BF16_DOT2 1
#endif
#endif

#ifdef USE_BF16_DOT2
typedef __bf16 bf16x2_t __attribute__((ext_vector_type(2)));
__device__ __forceinline__ float dot2bf(uint32_t w, uint32_t c, float acc) {
  return __builtin_amdgcn_fdot2_f32_bf16(__builtin_bit_cast(bf16x2_t, w),
                                         __builtin_bit_cast(bf16x2_t, c), acc, false);
}
#else
__device__ __forceinline__ float dot2bf(uint32_t w, uint32_t c, float acc) {
  float w0 = __uint_as_float(w << 16);
  float w1 = __uint_as_float(w & 0xffff0000u);
  float c0 = __uint_as_float(c << 16);
  float c1 = __uint_as_float(c & 0xffff0000u);
  return fmaf(w1, c1, fmaf(w0, c0, acc));
}
#endif

__device__ __forceinline__ void gl_lds16(const void* g, void* l) {
  __builtin_amdgcn_global_load_lds((const __attribute__((address_space(1))) void*)g,
                                   (__attribute__((address_space(3))) void*)l,
                                   16, 0, 0);
}

typedef short v8s __attribute__((ext_vector_type(8)));
typedef float v4f __attribute__((ext_vector_type(4)));

// ---------- K0: gather emb -> cat[:,512:1024] (bf16), convert weights to bf16 ----------
__global__ __launch_bounds__(256) void prep_kernel(
    const int* __restrict__ inp, const float* __restrict__ table,
    const float* __restrict__ Wsl, const float* __restrict__ Wsr,
    const float* __restrict__ Wl,  const float* __restrict__ Wr,
    const float* __restrict__ Wmax,
    uint16_t* __restrict__ cat, uint16_t* __restrict__ wslb,
    uint16_t* __restrict__ wsrb, uint16_t* __restrict__ wlb,
    uint16_t* __restrict__ wrb, uint16_t* __restrict__ wmaxb)
{
  const int blk = blockIdx.x, t = threadIdx.x;
  if (blk < 8192) {
    const int r = blk * 4 + (t >> 6);
    const int lane = t & 63;
    const int token = inp[r];
    const float4* src = (const float4*)(table + (size_t)token * EMBD);
    uint16_t* dst = cat + (size_t)r * KCAT + 512;
#pragma unroll
    for (int p = 0; p < 2; ++p) {
      const int slot = lane + 64 * p;   // 0..127 float4 slots per row
      float4 v = src[slot];
      uint2 o;
      o.x = pk2(v.x, v.y);
      o.y = pk2(v.z, v.w);
      *(uint2*)(dst + slot * 4) = o;
    }
  } else {
    size_t flat = (size_t)(blk - 8192) * 2048 + (size_t)t * 8;
    const float* src; uint16_t* dst; size_t off;
    if (flat < 262144)       { src = Wsl;  dst = wslb;  off = flat; }
    else if (flat < 524288)  { src = Wsr;  dst = wsrb;  off = flat - 262144; }
    else if (flat < 786432)  { src = Wl;   dst = wlb;   off = flat - 524288; }
    else if (flat < 1048576) { src = Wr;   dst = wrb;   off = flat - 786432; }
    else                     { src = Wmax; dst = wmaxb; off = flat - 1048576; }
    float4 v0 = *(const float4*)(src + off);
    float4 v1 = *(const float4*)(src + off + 4);
    uint4 o;
    o.x = pk2(v0.x, v0.y); o.y = pk2(v0.z, v0.w);
    o.z = pk2(v1.x, v1.y); o.w = pk2(v1.z, v1.w);
    *(uint4*)(dst + off) = o;
  }
}

// ---------- GEMM (m97-style): C[M x 1024] = A[M x K] @ W^T, 128x128 tiles, BK=64 ----------
// MODE 0: out = A@W^T + bias -> bf16 store (proj GEMM, W split at n=512)
// MODE 1: v = tanh(A@W^T + bias); partial[mb][b][n] = max over the block's 2 s-rows
template<int MODE>
__global__ __launch_bounds__(256, 2) void gemm_kernel(
    const uint16_t* __restrict__ A, int lda, int K,
    const uint16_t* __restrict__ W0, const uint16_t* __restrict__ W1,
    const float* __restrict__ bias0, const float* __restrict__ bias1,
    uint16_t* __restrict__ outb, float* __restrict__ partial)
{
  __shared__ unsigned char smem[32768];
  uint16_t* lA = (uint16_t*)smem;            // 128x64 bf16 = 16 KB
  uint16_t* lW = (uint16_t*)(smem + 16384);  // 128x64 bf16 = 16 KB

  const int tid = threadIdx.x;
  const int mb = blockIdx.x, nb = blockIdx.y;
  const int m0 = mb * 128, n0 = nb * 128;

  const uint16_t* Wp = W0;
  const float* biasp = bias0;
  int nr0 = n0;
  if (MODE == 0 && n0 >= 512) { Wp = W1; biasp = bias1; nr0 = n0 - 512; }

  const int w = tid >> 6, lane = tid & 63;
  const int mw = w & 1, nw = w >> 1;

  v4f acc[4][4];
#pragma unroll
  for (int i = 0; i < 4; ++i)
#pragma unroll
    for (int j = 0; j < 4; ++j) {
      v4f z = {0.f, 0.f, 0.f, 0.f};
      acc[i][j] = z;
    }

  const int r_st = tid >> 3;   // + p*32
  const int u_st = tid & 7;

  for (int kk = 0; kk < K; kk += 64) {
    __syncthreads();
#pragma unroll
    for (int p = 0; p < 4; ++p) {
      const int r = p * 32 + r_st;
      gl_lds16(A + (size_t)(m0 + r) * lda + kk + u_st * 8, lA + (p * 256 + tid) * 8);
    }
#pragma unroll
    for (int p = 0; p < 4; ++p) {
      const int r = p * 32 + r_st;
      gl_lds16(Wp + (size_t)(nr0 + r) * K + kk + u_st * 8, lW + (p * 256 + tid) * 8);
    }
    __syncthreads();
#pragma unroll
    for (int ks = 0; ks < 2; ++ks) {
      v8s af[4], wf[4];
#pragma unroll
      for (int i = 0; i < 4; ++i)
        af[i] = *(const v8s*)&lA[(mw * 64 + i * 16 + (lane & 15)) * 64 + ks * 32 + (lane >> 4) * 8];
#pragma unroll
      for (int j = 0; j < 4; ++j)
        wf[j] = *(const v8s*)&lW[(nw * 64 + j * 16 + (lane & 15)) * 64 + ks * 32 + (lane >> 4) * 8];
#pragma unroll
      for (int i = 0; i < 4; ++i)
#pragma unroll
        for (int j = 0; j < 4; ++j)
          acc[i][j] = __builtin_amdgcn_mfma_f32_16x16x32_bf16(af[i], wf[j], acc[i][j], 0, 0, 0);
    }
  }

  __syncthreads();  // all LDS frag reads done before epilogue reuse

  if (MODE == 0) {
#pragma unroll
    for (int i = 0; i < 4; ++i)
#pragma unroll
      for (int j = 0; j < 4; ++j) {
        const int nl = nw * 64 + j * 16 + (lane & 15);
        const float bv = biasp[nr0 + nl];
        const int colg = n0 + nl;
#pragma unroll
        for (int r = 0; r < 4; ++r) {
          const int rowg = m0 + mw * 64 + i * 16 + (lane >> 4) * 4 + r;
          outb[(size_t)rowg * 1024 + colg] = f2bf(acc[i][j][r] + bv);
        }
      }
  } else {
    float* lred = (float*)smem;   // 64 b x 128 n f32 = 32 KB
    if (mw == 1) {
#pragma unroll
      for (int i = 0; i < 4; ++i)
#pragma unroll
        for (int j = 0; j < 4; ++j) {
          const int nl = nw * 64 + j * 16 + (lane & 15);
          const float bv = biasp[nr0 + nl];
#pragma unroll
          for (int r = 0; r < 4; ++r) {
            const int bl = i * 16 + (lane >> 4) * 4 + r;
            lred[bl * 128 + nl] = tanhf(acc[i][j][r] + bv);
          }
        }
    }
    __syncthreads();
    if (mw == 0) {
#pragma unroll
      for (int i = 0; i < 4; ++i)
#pragma unroll
        for (int j = 0; j < 4; ++j) {
          const int nl = nw * 64 + j * 16 + (lane & 15);
          const float bv = biasp[nr0 + nl];
#pragma unroll
          for (int r = 0; r < 4; ++r) {
            const int bl = i * 16 + (lane >> 4) * 4 + r;
            const float v = tanhf(acc[i][j][r] + bv);
            partial[((size_t)mb * 64 + bl) * 1024 + n0 + nl] = fmaxf(v, lred[bl * 128 + nl]);
          }
        }
    }
  }
}

// ---------- K2: bidirectional recurrence ----------
// 256 blocks x 512 threads: (batch b, dir d, half hf). Thread = (row 0..255, kq 0..1).
// W chunk: 256 rows x 256-k window -> wreg[128] packed bf16 pairs (512 B/thread).
// amdgpu_waves_per_eu(2,2): pins allocator budget at 512/2 = 256 VGPRs so wreg
// STAYS IN REGISTERS (rounds 1-2 spilled: allocator targets 4 waves/EU by default
// and __launch_bounds__ min-waves does not override it; 84 GB scratch FETCH).
__global__ __attribute__((amdgpu_flat_work_group_size(512, 512)))
__attribute__((amdgpu_waves_per_eu(2, 2)))
void scan_kernel(
    const uint16_t* __restrict__ ee,     // [32768][1024] bf16: ls | rs
    const uint16_t* __restrict__ wlb, const uint16_t* __restrict__ wrb,
    const float* __restrict__ bl, const float* __restrict__ br,
    const float* __restrict__ cl0, const float* __restrict__ cr0,
    uint16_t* __restrict__ cat,
    uint32_t* __restrict__ cbuf, uint32_t* __restrict__ flags)
{
  const int tid = threadIdx.x;
  const int bid = blockIdx.x;
  const int hf = (bid >> 3) & 1;
  const int id = (bid & 7) * 16 + (bid >> 4);   // 0..127 == (b,d)
  const int b = id >> 1, d = id & 1;
  const int pbid = bid ^ 8;           // partner: same XCD under bid%8 round-robin

  const int w = tid >> 6, lane = tid & 63;
  const int rloc = (w & 3) * 64 + lane;  // 0..255  (row within half)
  const int kq = w >> 2;                 // 0/1: k window 256
  const int h = hf * 256 + rloc;

  // W chunk: 128 bf16-pairs in registers (bf16 source from prep)
  const uint16_t* wsrc = (d ? wrb : wlb) + (size_t)h * HIDD + kq * 256;
  uint32_t wreg[128];
#pragma unroll
  for (int j = 0; j < 32; ++j) {
    uint4 q = ((const uint4*)wsrc)[j];
    wreg[4 * j + 0] = q.x; wreg[4 * j + 1] = q.y;
    wreg[4 * j + 2] = q.z; wreg[4 * j + 3] = q.w;
  }

  __shared__ uint32_t cpair[256];   // full c (512 bf16) as pairs
  __shared__ float2 part2[256];     // per-row partial sums (kq0,kq1)

  if (tid < 256) {
    const float* c0v = d ? cr0 : cl0;
    float2 cv = ((const float2*)c0v)[tid];
    cpair[tid] = pk2(cv.x, cv.y);
  }
  float2 biasv = {0.f, 0.f};
  if (tid < 128) {
    const float* bvec = (d ? br : bl) + hf * 256;
    biasv = ((const float2*)bvec)[tid];
  }
  __syncthreads();

  // 2-deep ee prefetch so barrier vmcnt(0) drains never wait on HBM
  const size_t ecol = (size_t)(d * 512 + hf * 256 + 2 * (tid & 127));
  uint32_t ep0 = 0, ep1 = 0;
  if (tid < 128) {
    const int s0i = d ? 511 : 0;
    const int s1i = d ? 510 : 1;
    ep0 = *(const uint32_t*)&ee[(size_t)(s0i * BB + b) * 1024 + ecol];
    ep1 = *(const uint32_t*)&ee[(size_t)(s1i * BB + b) * 1024 + ecol];
  }

  for (int i = 0; i < 512; ++i) {
    const int s = d ? (511 - i) : i;
    uint32_t ep2 = 0;
    if (tid < 128) {
      const int i2 = (i + 2) & 511;
      const int s2 = d ? (511 - i2) : i2;
      ep2 = *(const uint32_t*)&ee[(size_t)(s2 * BB + b) * 1024 + ecol];
    }

    // dot: row rloc, k window [kq*256, +256). Wave-uniform LDS reads (broadcast).
    const uint32_t* cb = &cpair[kq * 128];
    float a0 = 0.f, a1 = 0.f, a2 = 0.f, a3 = 0.f;
#pragma unroll
    for (int j = 0; j < 32; ++j) {
      uint4 cc = *(const uint4*)(cb + 4 * j);
      a0 = dot2bf(wreg[4 * j + 0], cc.x, a0);
      a1 = dot2bf(wreg[4 * j + 1], cc.y, a1);
      a2 = dot2bf(wreg[4 * j + 2], cc.z, a2);
      a3 = dot2bf(wreg[4 * j + 3], cc.w, a3);
    }
    ((float*)&part2[rloc])[kq] = (a0 + a1) + (a2 + a3);
    __syncthreads();

    // finalize rows 2t, 2t+1; publish own half (cbuf only; cat store deferred)
    uint32_t pr = 0;
    if (tid < 128) {
      float4 p4 = *(const float4*)&part2[2 * tid];
      float s0 = p4.x + p4.y + biasv.x + bf2f(ep0 & 0xffffu);
      float s1 = p4.z + p4.w + biasv.y + bf2f(ep0 >> 16);
      pr = pk2(tanhf(s0), tanhf(s1));
      cpair[hf * 128 + tid] = pr;
      if (i != 511) {
        uint32_t* slot = cbuf + ((((i & 1) * 128 + id) * 2 + hf) * 128) + tid;
        __hip_atomic_store(slot, pr, __ATOMIC_RELAXED, __HIP_MEMORY_SCOPE_AGENT);
      }
    }

    if (i == 511) {
      if (tid < 128) {
        const int col = (d ? 1024 : 0) + hf * 256 + 2 * tid;
        *(uint32_t*)&cat[(size_t)(s * BB + b) * KCAT + col] = pr;
      }
      break;
    }

    __syncthreads();   // drains producers' cbuf stores (vmcnt(0)) before flag
    if (tid == 0)
      __hip_atomic_store(&flags[bid], (uint32_t)(i + 1), __ATOMIC_RELEASE, __HIP_MEMORY_SCOPE_AGENT);

    if (tid < 128) {
      // deferred cat store — off the handshake critical path
      const int col = (d ? 1024 : 0) + hf * 256 + 2 * tid;
      *(uint32_t*)&cat[(size_t)(s * BB + b) * KCAT + col] = pr;
      while (__hip_atomic_load(&flags[pbid], __ATOMIC_ACQUIRE, __HIP_MEMORY_SCOPE_AGENT) < (uint32_t)(i + 1)) {
        __builtin_amdgcn_s_sleep(1);
      }
      const uint32_t* pslot = cbuf + ((((i & 1) * 128 + id) * 2 + (hf ^ 1)) * 128) + tid;
      uint32_t pv = __hip_atomic_load(pslot, __ATOMIC_RELAXED, __HIP_MEMORY_SCOPE_AGENT);
      cpair[(hf ^ 1) * 128 + tid] = pv;
    }
    __syncthreads();

    ep0 = ep1; ep1 = ep2;
  }
}

// ---------- K4: max-reduce partials, classifier, log_softmax ----------
__global__ __launch_bounds__(256) void final_kernel(
    const float* __restrict__ partial, const float* __restrict__ Wdoc,
    const float* __restrict__ bdoc, float* __restrict__ out)
{
  const int b = blockIdx.x, t = threadIdx.x;
  __shared__ float ym[1024];
  __shared__ float lg[32];
  float m0 = -2.f, m1 = -2.f, m2 = -2.f, m3 = -2.f;
  for (int mg = 0; mg < 256; ++mg) {
    const float* p = partial + ((size_t)mg * 64 + b) * 1024;
    m0 = fmaxf(m0, p[t]);
    m1 = fmaxf(m1, p[t + 256]);
    m2 = fmaxf(m2, p[t + 512]);
    m3 = fmaxf(m3, p[t + 768]);
  }
  ym[t] = m0; ym[t + 256] = m1; ym[t + 512] = m2; ym[t + 768] = m3;
  __syncthreads();
  if (t < NCLS) {
    const float* wr = Wdoc + (size_t)t * 1024;
    float a0 = 0.f, a1 = 0.f, a2 = 0.f, a3 = 0.f;
    for (int n = 0; n < 1024; n += 4) {
      a0 = fmaf(ym[n], wr[n], a0);
      a1 = fmaf(ym[n + 1], wr[n + 1], a1);
      a2 = fmaf(ym[n + 2], wr[n + 2], a2);
      a3 = fmaf(ym[n + 3], wr[n + 3], a3);
    }
    lg[t] = (a0 + a1) + (a2 + a3) + bdoc[t];
  }
  __syncthreads();
  if (t < NCLS) {
    float mx = -1e30f;
    for (int c = 0; c < NCLS; ++c) mx = fmaxf(mx, lg[c]);
    float ssum = 0.f;
    for (int c = 0; c < NCLS; ++c) ssum += expf(lg[c] - mx);
    out[b * NCLS + t] = lg[t] - mx - logf(ssum);
  }
}

// ---------- launch ----------
extern "C" void kernel_launch(void* const* d_in, const int* in_sizes, int n_in,
                              void* d_out, int out_size, void* d_ws, size_t ws_size,
                              hipStream_t stream) {
  const int*   inp   = (const int*)  d_in[0];
  const float* table = (const float*)d_in[1];
  const float* cl0   = (const float*)d_in[2];
  const float* cr0   = (const float*)d_in[3];
  const float* Wl    = (const float*)d_in[4];
  const float* bl    = (const float*)d_in[5];
  const float* Wr    = (const float*)d_in[6];
  const float* br    = (const float*)d_in[7];
  const float* Wsl   = (const float*)d_in[8];
  const float* bsl   = (const float*)d_in[9];
  const float* Wsr   = (const float*)d_in[10];
  const float* bsr   = (const float*)d_in[11];
  const float* Wmax  = (const float*)d_in[12];
  const float* bmax  = (const float*)d_in[13];
  const float* Wdoc  = (const float*)d_in[14];
  const float* bdoc  = (const float*)d_in[15];

  uint8_t* ws = (uint8_t*)d_ws;
  uint16_t* cat     = (uint16_t*)(ws);                 // 32768*1536*2 = 100663296
  uint16_t* ee      = (uint16_t*)(ws + 100663296);     // 32768*1024*2 = 67108864
  float*    partial = (float*)   (ws + 167772160);     // 256*64*1024*4 = 67108864
  uint16_t* wslb    = (uint16_t*)(ws + 234881024);     // 524288
  uint16_t* wsrb    = (uint16_t*)(ws + 235405312);     // 524288
  uint16_t* wmaxb   = (uint16_t*)(ws + 235929600);     // 3145728
  uint16_t* wlb     = (uint16_t*)(ws + 239075328);     // 524288
  uint16_t* wrb     = (uint16_t*)(ws + 239599616);     // 524288
  uint32_t* cbuf    = (uint32_t*)(ws + 240123904);     // 262144
  uint32_t* flags   = (uint32_t*)(ws + 240386048);     // 1024

  hipMemsetAsync(flags, 0, 1024, stream);
  prep_kernel<<<9472, 256, 0, stream>>>(inp, table, Wsl, Wsr, Wl, Wr, Wmax,
                                        cat, wslb, wsrb, wlb, wrb, wmaxb);
  gemm_kernel<0><<<dim3(256, 8), 256, 0, stream>>>(cat + 512, KCAT, 512, wslb, wsrb,
                                                   bsl, bsr, ee, nullptr);
  scan_kernel<<<256, 512, 0, stream>>>(ee, wlb, wrb, bl, br, cl0, cr0, cat, cbuf, flags);
  gemm_kernel<1><<<dim3(256, 8), 256, 0, stream>>>(cat, KCAT, KCAT, wmaxb, nullptr,
                                                   bmax, nullptr, nullptr, partial);
  final_kernel<<<64, 256, 0, stream>>>(partial, Wdoc, bdoc, (float*)d_out);
}

// Round 4
// 4716.667 us; speedup vs baseline: 1.1885x; 1.1885x over previous
//
#include <hip/hip_runtime.h>
#include <hip/hip_bf16.h>
#include <cstdint>
#include <cstddef>

// Problem dims
#define SS   512
#define BB   64
#define EMBD 512
#define HIDD 512
#define MAXD 1024
#define NCLS 20
#define KCAT 1536
#define ROWS (SS*BB)   // 32768

// ---------- small helpers ----------
__device__ __forceinline__ uint16_t f2bf(float f) {
  uint32_t u = __float_as_uint(f);
  uint32_t r = u + 0x7fffu + ((u >> 16) & 1u);
  return (uint16_t)(r >> 16);
}
__device__ __forceinline__ float bf2f(uint32_t h) {
  return __uint_as_float(h << 16);
}
__device__ __forceinline__ uint32_t pk2(float a, float b) {
  return (uint32_t)f2bf(a) | ((uint32_t)f2bf(b) << 16);
}

#if defined(__has_builtin)
#if __has_builtin(__builtin_amdgcn_fdot2_f32_bf16)
#define USE_BF16_DOT2 1
#endif
#endif

#ifdef USE_BF16_DOT2
typedef __bf16 bf16x2_t __attribute__((ext_vector_type(2)));
__device__ __forceinline__ float dot2bf(uint32_t w, uint32_t c, float acc) {
  return __builtin_amdgcn_fdot2_f32_bf16(__builtin_bit_cast(bf16x2_t, w),
                                         __builtin_bit_cast(bf16x2_t, c), acc, false);
}
#else
__device__ __forceinline__ float dot2bf(uint32_t w, uint32_t c, float acc) {
  float w0 = __uint_as_float(w << 16);
  float w1 = __uint_as_float(w & 0xffff0000u);
  float c0 = __uint_as_float(c << 16);
  float c1 = __uint_as_float(c & 0xffff0000u);
  return fmaf(w1, c1, fmaf(w0, c0, acc));
}
#endif

__device__ __forceinline__ void gl_lds16(const void* g, void* l) {
  __builtin_amdgcn_global_load_lds((const __attribute__((address_space(1))) void*)g,
                                   (__attribute__((address_space(3))) void*)l,
                                   16, 0, 0);
}

typedef short v8s __attribute__((ext_vector_type(8)));
typedef float v4f __attribute__((ext_vector_type(4)));

// ---------- K0: gather emb -> cat[:,512:1024] (bf16), convert weights to bf16 ----------
__global__ __launch_bounds__(256) void prep_kernel(
    const int* __restrict__ inp, const float* __restrict__ table,
    const float* __restrict__ Wsl, const float* __restrict__ Wsr,
    const float* __restrict__ Wl,  const float* __restrict__ Wr,
    const float* __restrict__ Wmax,
    uint16_t* __restrict__ cat, uint16_t* __restrict__ wslb,
    uint16_t* __restrict__ wsrb, uint16_t* __restrict__ wlb,
    uint16_t* __restrict__ wrb, uint16_t* __restrict__ wmaxb)
{
  const int blk = blockIdx.x, t = threadIdx.x;
  if (blk < 8192) {
    const int r = blk * 4 + (t >> 6);
    const int lane = t & 63;
    const int token = inp[r];
    const float4* src = (const float4*)(table + (size_t)token * EMBD);
    uint16_t* dst = cat + (size_t)r * KCAT + 512;
#pragma unroll
    for (int p = 0; p < 2; ++p) {
      const int slot = lane + 64 * p;   // 0..127 float4 slots per row
      float4 v = src[slot];
      uint2 o;
      o.x = pk2(v.x, v.y);
      o.y = pk2(v.z, v.w);
      *(uint2*)(dst + slot * 4) = o;
    }
  } else {
    size_t flat = (size_t)(blk - 8192) * 2048 + (size_t)t * 8;
    const float* src; uint16_t* dst; size_t off;
    if (flat < 262144)       { src = Wsl;  dst = wslb;  off = flat; }
    else if (flat < 524288)  { src = Wsr;  dst = wsrb;  off = flat - 262144; }
    else if (flat < 786432)  { src = Wl;   dst = wlb;   off = flat - 524288; }
    else if (flat < 1048576) { src = Wr;   dst = wrb;   off = flat - 786432; }
    else                     { src = Wmax; dst = wmaxb; off = flat - 1048576; }
    float4 v0 = *(const float4*)(src + off);
    float4 v1 = *(const float4*)(src + off + 4);
    uint4 o;
    o.x = pk2(v0.x, v0.y); o.y = pk2(v0.z, v0.w);
    o.z = pk2(v1.x, v1.y); o.w = pk2(v1.z, v1.w);
    *(uint4*)(dst + off) = o;
  }
}

// ---------- GEMM (m97-style): C[M x 1024] = A[M x K] @ W^T, 128x128 tiles, BK=64 ----------
// MODE 0: out = A@W^T + bias -> bf16 store (proj GEMM, W split at n=512)
// MODE 1: v = tanh(A@W^T + bias); partial[mb][b][n] = max over the block's 2 s-rows
template<int MODE>
__global__ __launch_bounds__(256, 2) void gemm_kernel(
    const uint16_t* __restrict__ A, int lda, int K,
    const uint16_t* __restrict__ W0, const uint16_t* __restrict__ W1,
    const float* __restrict__ bias0, const float* __restrict__ bias1,
    uint16_t* __restrict__ outb, float* __restrict__ partial)
{
  __shared__ unsigned char smem[32768];
  uint16_t* lA = (uint16_t*)smem;            // 128x64 bf16 = 16 KB
  uint16_t* lW = (uint16_t*)(smem + 16384);  // 128x64 bf16 = 16 KB

  const int tid = threadIdx.x;
  const int mb = blockIdx.x, nb = blockIdx.y;
  const int m0 = mb * 128, n0 = nb * 128;

  const uint16_t* Wp = W0;
  const float* biasp = bias0;
  int nr0 = n0;
  if (MODE == 0 && n0 >= 512) { Wp = W1; biasp = bias1; nr0 = n0 - 512; }

  const int w = tid >> 6, lane = tid & 63;
  const int mw = w & 1, nw = w >> 1;

  v4f acc[4][4];
#pragma unroll
  for (int i = 0; i < 4; ++i)
#pragma unroll
    for (int j = 0; j < 4; ++j) {
      v4f z = {0.f, 0.f, 0.f, 0.f};
      acc[i][j] = z;
    }

  const int r_st = tid >> 3;   // + p*32
  const int u_st = tid & 7;

  for (int kk = 0; kk < K; kk += 64) {
    __syncthreads();
#pragma unroll
    for (int p = 0; p < 4; ++p) {
      const int r = p * 32 + r_st;
      gl_lds16(A + (size_t)(m0 + r) * lda + kk + u_st * 8, lA + (p * 256 + tid) * 8);
    }
#pragma unroll
    for (int p = 0; p < 4; ++p) {
      const int r = p * 32 + r_st;
      gl_lds16(Wp + (size_t)(nr0 + r) * K + kk + u_st * 8, lW + (p * 256 + tid) * 8);
    }
    __syncthreads();
#pragma unroll
    for (int ks = 0; ks < 2; ++ks) {
      v8s af[4], wf[4];
#pragma unroll
      for (int i = 0; i < 4; ++i)
        af[i] = *(const v8s*)&lA[(mw * 64 + i * 16 + (lane & 15)) * 64 + ks * 32 + (lane >> 4) * 8];
#pragma unroll
      for (int j = 0; j < 4; ++j)
        wf[j] = *(const v8s*)&lW[(nw * 64 + j * 16 + (lane & 15)) * 64 + ks * 32 + (lane >> 4) * 8];
#pragma unroll
      for (int i = 0; i < 4; ++i)
#pragma unroll
        for (int j = 0; j < 4; ++j)
          acc[i][j] = __builtin_amdgcn_mfma_f32_16x16x32_bf16(af[i], wf[j], acc[i][j], 0, 0, 0);
    }
  }

  __syncthreads();  // all LDS frag reads done before epilogue reuse

  if (MODE == 0) {
#pragma unroll
    for (int i = 0; i < 4; ++i)
#pragma unroll
      for (int j = 0; j < 4; ++j) {
        const int nl = nw * 64 + j * 16 + (lane & 15);
        const float bv = biasp[nr0 + nl];
        const int colg = n0 + nl;
#pragma unroll
        for (int r = 0; r < 4; ++r) {
          const int rowg = m0 + mw * 64 + i * 16 + (lane >> 4) * 4 + r;
          outb[(size_t)rowg * 1024 + colg] = f2bf(acc[i][j][r] + bv);
        }
      }
  } else {
    float* lred = (float*)smem;   // 64 b x 128 n f32 = 32 KB
    if (mw == 1) {
#pragma unroll
      for (int i = 0; i < 4; ++i)
#pragma unroll
        for (int j = 0; j < 4; ++j) {
          const int nl = nw * 64 + j * 16 + (lane & 15);
          const float bv = biasp[nr0 + nl];
#pragma unroll
          for (int r = 0; r < 4; ++r) {
            const int bl = i * 16 + (lane >> 4) * 4 + r;
            lred[bl * 128 + nl] = tanhf(acc[i][j][r] + bv);
          }
        }
    }
    __syncthreads();
    if (mw == 0) {
#pragma unroll
      for (int i = 0; i < 4; ++i)
#pragma unroll
        for (int j = 0; j < 4; ++j) {
          const int nl = nw * 64 + j * 16 + (lane & 15);
          const float bv = biasp[nr0 + nl];
#pragma unroll
          for (int r = 0; r < 4; ++r) {
            const int bl = i * 16 + (lane >> 4) * 4 + r;
            const float v = tanhf(acc[i][j][r] + bv);
            partial[((size_t)mb * 64 + bl) * 1024 + n0 + nl] = fmaxf(v, lred[bl * 128 + nl]);
          }
        }
    }
  }
}

// ---------- K2: bidirectional recurrence, W-in-LDS (spill-proof) ----------
// 256 blocks x 512 threads: block = (batch-pair pb 0..31, dir d, h-quarter qh 0..3).
// W quarter (128 h x 512 k bf16 = 130 KB padded) lives ENTIRELY in LDS -> ~60 VGPRs,
// no spill at any allocator budget (rounds 1-3: W-in-VGPR always spilled to scratch).
// Each block advances 2 batches for its 128 h. Fan-in-3 gather exchange of c quarters
// via agent-scope atomics (pattern correctness-validated rounds 1-3).
__global__ __launch_bounds__(512) void scan_kernel(
    const uint16_t* __restrict__ ee,     // [32768][1024] bf16: ls | rs
    const uint16_t* __restrict__ wlb, const uint16_t* __restrict__ wrb,
    const float* __restrict__ bl, const float* __restrict__ br,
    const float* __restrict__ cl0, const float* __restrict__ cr0,
    uint16_t* __restrict__ cat,
    uint32_t* __restrict__ cbuf, uint32_t* __restrict__ flags)
{
  const int tid = threadIdx.x;
  const int bid = blockIdx.x;
  const int qh = bid >> 6;          // h-quarter 0..3 (partners differ by 64 -> same bid%8)
  const int pb = (bid >> 1) & 31;   // batch pair
  const int d  = bid & 1;
  const int b0 = pb * 2;

  const int h2 = tid & 127;         // row within quarter
  const int kq = tid >> 7;          // 0..3: k-window of 128

  // W rows padded to 260 u32 (stride 1040 B -> lane bank-stride 4: conflict-free b128 groups)
  __shared__ uint32_t wlds[128 * 260];   // 133120 B
  __shared__ uint32_t cpair[2 * 256];    // c per batch as 256 bf16-pairs
  __shared__ float    part[2 * 128 * 4]; // [b2][h2][kq] partial sums

  // ---- stage W quarter into LDS ----
  {
    const uint16_t* wsrc = (d ? wrb : wlb) + (size_t)(qh * 128 + h2) * HIDD + kq * 128;
    uint32_t* dstrow = &wlds[h2 * 260 + kq * 64];
#pragma unroll
    for (int j = 0; j < 16; ++j) {
      uint4 q = ((const uint4*)wsrc)[j];
      *(uint4*)(dstrow + j * 4) = q;
    }
  }
  // init c for both batches (same init vector)
  {
    const int b2 = tid >> 8, idx = tid & 255;
    const float* c0v = d ? cr0 : cl0;
    float2 cv = ((const float2*)c0v)[idx];
    cpair[b2 * 256 + idx] = pk2(cv.x, cv.y);
  }
  float2 biasv = {0.f, 0.f};
  if (tid < 128) {
    const float* bvec = d ? br : bl;
    biasv = ((const float2*)bvec)[qh * 64 + (tid & 63)];
  }
  __syncthreads();

  // finalize-thread geometry: b2 = tid>>6, p = tid&63 -> h pair (2p, 2p+1) of quarter
  const int fb2 = tid >> 6;
  const int fp  = tid & 63;
  const size_t ecol = (size_t)(d * 512 + qh * 128 + 2 * fp);

  // 2-deep ee prefetch ring
  uint32_t ep0 = 0, ep1 = 0;
  if (tid < 128) {
    const int s0i = d ? 511 : 0;
    const int s1i = d ? 510 : 1;
    ep0 = *(const uint32_t*)&ee[(size_t)(s0i * BB + b0 + fb2) * 1024 + ecol];
    ep1 = *(const uint32_t*)&ee[(size_t)(s1i * BB + b0 + fb2) * 1024 + ecol];
  }

  for (int i = 0; i < 512; ++i) {
    const int s = d ? (511 - i) : i;
    uint32_t ep2 = 0;
    if (tid < 128) {
      const int i2 = (i + 2) & 511;
      const int s2 = d ? (511 - i2) : i2;
      ep2 = *(const uint32_t*)&ee[(size_t)(s2 * BB + b0 + fb2) * 1024 + ecol];
    }

    // dot: row h2, k-window [kq*128,+128), both batches. W per-lane b128; c broadcast.
    {
      const uint32_t* wr_ = &wlds[h2 * 260 + kq * 64];
      const uint32_t* ca_ = &cpair[kq * 64];
      const uint32_t* cb_ = &cpair[256 + kq * 64];
      float a00 = 0.f, a01 = 0.f, a10 = 0.f, a11 = 0.f;
#pragma unroll
      for (int j = 0; j < 16; ++j) {
        uint4 w4 = *(const uint4*)(wr_ + j * 4);
        uint4 c4 = *(const uint4*)(ca_ + j * 4);
        uint4 d4 = *(const uint4*)(cb_ + j * 4);
        a00 = dot2bf(w4.x, c4.x, a00); a01 = dot2bf(w4.y, c4.y, a01);
        a00 = dot2bf(w4.z, c4.z, a00); a01 = dot2bf(w4.w, c4.w, a01);
        a10 = dot2bf(w4.x, d4.x, a10); a11 = dot2bf(w4.y, d4.y, a11);
        a10 = dot2bf(w4.z, d4.z, a10); a11 = dot2bf(w4.w, d4.w, a11);
      }
      part[(h2 << 2) + kq]       = a00 + a01;
      part[512 + (h2 << 2) + kq] = a10 + a11;
    }
    __syncthreads();

    // finalize: tid<128 -> one c-pair of one batch
    uint32_t pr = 0;
    if (tid < 128) {
      float4 q0 = *(const float4*)&part[fb2 * 512 + (2 * fp) * 4];
      float4 q1 = *(const float4*)&part[fb2 * 512 + (2 * fp + 1) * 4];
      float s0 = ((q0.x + q0.y) + (q0.z + q0.w)) + biasv.x + bf2f(ep0 & 0xffffu);
      float s1 = ((q1.x + q1.y) + (q1.z + q1.w)) + biasv.y + bf2f(ep0 >> 16);
      pr = pk2(tanhf(s0), tanhf(s1));
      cpair[fb2 * 256 + qh * 64 + fp] = pr;
      if (i != 511) {
        uint32_t* slot = cbuf + (((i & 1) * 256 + bid) * 128) + tid;
        __hip_atomic_store(slot, pr, __ATOMIC_RELAXED, __HIP_MEMORY_SCOPE_AGENT);
      }
    }

    if (i == 511) {
      if (tid < 128) {
        const int col = (d ? 1024 : 0) + qh * 128 + 2 * fp;
        *(uint32_t*)&cat[(size_t)(s * BB + b0 + fb2) * KCAT + col] = pr;
      }
      break;
    }

    __syncthreads();   // vmcnt(0) drain: cbuf publish complete before flag
    if (tid == 0)
      __hip_atomic_store(&flags[bid], (uint32_t)(i + 1), __ATOMIC_RELEASE, __HIP_MEMORY_SCOPE_AGENT);

    if (tid < 128) {
      // deferred cat store — off the handshake critical path
      const int col = (d ? 1024 : 0) + qh * 128 + 2 * fp;
      *(uint32_t*)&cat[(size_t)(s * BB + b0 + fb2) * KCAT + col] = pr;
    }
    if (tid < 3) {
      // lanes 0..2 poll the three partner quarters in parallel
      const int pq = (qh + 1 + tid) & 3;
      const int pbid = (pq << 6) | (pb << 1) | d;
      while (__hip_atomic_load(&flags[pbid], __ATOMIC_ACQUIRE, __HIP_MEMORY_SCOPE_AGENT) < (uint32_t)(i + 1)) {
        __builtin_amdgcn_s_sleep(1);
      }
    }
    __syncthreads();
    if (tid < 384) {
      const int pi = tid >> 7;        // partner 0..2
      const int j  = tid & 127;       // u32 within slot: b2=j>>6, p=j&63
      const int pq = (qh + 1 + pi) & 3;
      const int pbid = (pq << 6) | (pb << 1) | d;
      uint32_t pv = __hip_atomic_load(cbuf + (((i & 1) * 256 + pbid) * 128) + j,
                                      __ATOMIC_RELAXED, __HIP_MEMORY_SCOPE_AGENT);
      cpair[(j >> 6) * 256 + pq * 64 + (j & 63)] = pv;
    }
    __syncthreads();

    ep0 = ep1; ep1 = ep2;
  }
}

// ---------- K4: max-reduce partials, classifier, log_softmax ----------
__global__ __launch_bounds__(256) void final_kernel(
    const float* __restrict__ partial, const float* __restrict__ Wdoc,
    const float* __restrict__ bdoc, float* __restrict__ out)
{
  const int b = blockIdx.x, t = threadIdx.x;
  __shared__ float ym[1024];
  __shared__ float lg[32];
  float m0 = -2.f, m1 = -2.f, m2 = -2.f, m3 = -2.f;
  for (int mg = 0; mg < 256; ++mg) {
    const float* p = partial + ((size_t)mg * 64 + b) * 1024;
    m0 = fmaxf(m0, p[t]);
    m1 = fmaxf(m1, p[t + 256]);
    m2 = fmaxf(m2, p[t + 512]);
    m3 = fmaxf(m3, p[t + 768]);
  }
  ym[t] = m0; ym[t + 256] = m1; ym[t + 512] = m2; ym[t + 768] = m3;
  __syncthreads();
  if (t < NCLS) {
    const float* wr = Wdoc + (size_t)t * 1024;
    float a0 = 0.f, a1 = 0.f, a2 = 0.f, a3 = 0.f;
    for (int n = 0; n < 1024; n += 4) {
      a0 = fmaf(ym[n], wr[n], a0);
      a1 = fmaf(ym[n + 1], wr[n + 1], a1);
      a2 = fmaf(ym[n + 2], wr[n + 2], a2);
      a3 = fmaf(ym[n + 3], wr[n + 3], a3);
    }
    lg[t] = (a0 + a1) + (a2 + a3) + bdoc[t];
  }
  __syncthreads();
  if (t < NCLS) {
    float mx = -1e30f;
    for (int c = 0; c < NCLS; ++c) mx = fmaxf(mx, lg[c]);
    float ssum = 0.f;
    for (int c = 0; c < NCLS; ++c) ssum += expf(lg[c] - mx);
    out[b * NCLS + t] = lg[t] - mx - logf(ssum);
  }
}

// ---------- launch ----------
extern "C" void kernel_launch(void* const* d_in, const int* in_sizes, int n_in,
                              void* d_out, int out_size, void* d_ws, size_t ws_size,
                              hipStream_t stream) {
  const int*   inp   = (const int*)  d_in[0];
  const float* table = (const float*)d_in[1];
  const float* cl0   = (const float*)d_in[2];
  const float* cr0   = (const float*)d_in[3];
  const float* Wl    = (const float*)d_in[4];
  const float* bl    = (const float*)d_in[5];
  const float* Wr    = (const float*)d_in[6];
  const float* br    = (const float*)d_in[7];
  const float* Wsl   = (const float*)d_in[8];
  const float* bsl   = (const float*)d_in[9];
  const float* Wsr   = (const float*)d_in[10];
  const float* bsr   = (const float*)d_in[11];
  const float* Wmax  = (const float*)d_in[12];
  const float* bmax  = (const float*)d_in[13];
  const float* Wdoc  = (const float*)d_in[14];
  const float* bdoc  = (const float*)d_in[15];

  uint8_t* ws = (uint8_t*)d_ws;
  uint16_t* cat     = (uint16_t*)(ws);                 // 32768*1536*2 = 100663296
  uint16_t* ee      = (uint16_t*)(ws + 100663296);     // 32768*1024*2 = 67108864
  float*    partial = (float*)   (ws + 167772160);     // 256*64*1024*4 = 67108864
  uint16_t* wslb    = (uint16_t*)(ws + 234881024);     // 524288
  uint16_t* wsrb    = (uint16_t*)(ws + 235405312);     // 524288
  uint16_t* wmaxb   = (uint16_t*)(ws + 235929600);     // 3145728
  uint16_t* wlb     = (uint16_t*)(ws + 239075328);     // 524288
  uint16_t* wrb     = (uint16_t*)(ws + 239599616);     // 524288
  uint32_t* cbuf    = (uint32_t*)(ws + 240123904);     // 262144 (2 parity x 256 bid x 512B)
  uint32_t* flags   = (uint32_t*)(ws + 240386048);     // 1024

  hipMemsetAsync(flags, 0, 1024, stream);
  prep_kernel<<<9472, 256, 0, stream>>>(inp, table, Wsl, Wsr, Wl, Wr, Wmax,
                                        cat, wslb, wsrb, wlb, wrb, wmaxb);
  gemm_kernel<0><<<dim3(256, 8), 256, 0, stream>>>(cat + 512, KCAT, 512, wslb, wsrb,
                                                   bsl, bsr, ee, nullptr);
  scan_kernel<<<256, 512, 0, stream>>>(ee, wlb, wrb, bl, br, cl0, cr0, cat, cbuf, flags);
  gemm_kernel<1><<<dim3(256, 8), 256, 0, stream>>>(cat, KCAT, KCAT, wmaxb, nullptr,
                                                   bmax, nullptr, nullptr, partial);
  final_kernel<<<64, 256, 0, stream>>>(partial, Wdoc, bdoc, (float*)d_out);
}

// Round 5
// 1460.957 us; speedup vs baseline: 3.8370x; 3.2285x over previous
//
#include <hip/hip_runtime.h>
#include <hip/hip_bf16.h>
#include <cstdint>
#include <cstddef>

// Problem dims
#define SS   512
#define BB   64
#define EMBD 512
#define HIDD 512
#define MAXD 1024
#define NCLS 20
#define KCAT 1536
#define ROWS (SS*BB)   // 32768

// ---------- small helpers ----------
__device__ __forceinline__ uint16_t f2bf(float f) {
  uint32_t u = __float_as_uint(f);
  uint32_t r = u + 0x7fffu + ((u >> 16) & 1u);
  return (uint16_t)(r >> 16);
}
__device__ __forceinline__ float bf2f(uint32_t h) {
  return __uint_as_float(h << 16);
}
__device__ __forceinline__ uint32_t pk2(float a, float b) {
  return (uint32_t)f2bf(a) | ((uint32_t)f2bf(b) << 16);
}

#if defined(__has_builtin)
#if __has_builtin(__builtin_amdgcn_fdot2_f32_bf16)
#define USE_BF16_DOT2 1
#endif
#endif

#ifdef USE_BF16_DOT2
typedef __bf16 bf16x2_t __attribute__((ext_vector_type(2)));
__device__ __forceinline__ float dot2bf(uint32_t w, uint32_t c, float acc) {
  return __builtin_amdgcn_fdot2_f32_bf16(__builtin_bit_cast(bf16x2_t, w),
                                         __builtin_bit_cast(bf16x2_t, c), acc, false);
}
#else
__device__ __forceinline__ float dot2bf(uint32_t w, uint32_t c, float acc) {
  float w0 = __uint_as_float(w << 16);
  float w1 = __uint_as_float(w & 0xffff0000u);
  float c0 = __uint_as_float(c << 16);
  float c1 = __uint_as_float(c & 0xffff0000u);
  return fmaf(w1, c1, fmaf(w0, c0, acc));
}
#endif

__device__ __forceinline__ void gl_lds16(const void* g, void* l) {
  __builtin_amdgcn_global_load_lds((const __attribute__((address_space(1))) void*)g,
                                   (__attribute__((address_space(3))) void*)l,
                                   16, 0, 0);
}

typedef short v8s __attribute__((ext_vector_type(8)));
typedef float v4f __attribute__((ext_vector_type(4)));

// ---------- K0: gather emb -> cat[:,512:1024] (bf16), convert weights to bf16 ----------
__global__ __launch_bounds__(256) void prep_kernel(
    const int* __restrict__ inp, const float* __restrict__ table,
    const float* __restrict__ Wsl, const float* __restrict__ Wsr,
    const float* __restrict__ Wl,  const float* __restrict__ Wr,
    const float* __restrict__ Wmax,
    uint16_t* __restrict__ cat, uint16_t* __restrict__ wslb,
    uint16_t* __restrict__ wsrb, uint16_t* __restrict__ wlb,
    uint16_t* __restrict__ wrb, uint16_t* __restrict__ wmaxb)
{
  const int blk = blockIdx.x, t = threadIdx.x;
  if (blk < 8192) {
    const int r = blk * 4 + (t >> 6);
    const int lane = t & 63;
    const int token = inp[r];
    const float4* src = (const float4*)(table + (size_t)token * EMBD);
    uint16_t* dst = cat + (size_t)r * KCAT + 512;
#pragma unroll
    for (int p = 0; p < 2; ++p) {
      const int slot = lane + 64 * p;   // 0..127 float4 slots per row
      float4 v = src[slot];
      uint2 o;
      o.x = pk2(v.x, v.y);
      o.y = pk2(v.z, v.w);
      *(uint2*)(dst + slot * 4) = o;
    }
  } else {
    size_t flat = (size_t)(blk - 8192) * 2048 + (size_t)t * 8;
    const float* src; uint16_t* dst; size_t off;
    if (flat < 262144)       { src = Wsl;  dst = wslb;  off = flat; }
    else if (flat < 524288)  { src = Wsr;  dst = wsrb;  off = flat - 262144; }
    else if (flat < 786432)  { src = Wl;   dst = wlb;   off = flat - 524288; }
    else if (flat < 1048576) { src = Wr;   dst = wrb;   off = flat - 786432; }
    else                     { src = Wmax; dst = wmaxb; off = flat - 1048576; }
    float4 v0 = *(const float4*)(src + off);
    float4 v1 = *(const float4*)(src + off + 4);
    uint4 o;
    o.x = pk2(v0.x, v0.y); o.y = pk2(v0.z, v0.w);
    o.z = pk2(v1.x, v1.y); o.w = pk2(v1.z, v1.w);
    *(uint4*)(dst + off) = o;
  }
}

// ---------- GEMM (m97-style): C[M x 1024] = A[M x K] @ W^T, 128x128 tiles, BK=64 ----------
// MODE 0: out = A@W^T + bias -> bf16 store (proj GEMM, W split at n=512)
// MODE 1: v = tanh(A@W^T + bias); partial[mb][b][n] = max over the block's 2 s-rows
template<int MODE>
__global__ __launch_bounds__(256, 2) void gemm_kernel(
    const uint16_t* __restrict__ A, int lda, int K,
    const uint16_t* __restrict__ W0, const uint16_t* __restrict__ W1,
    const float* __restrict__ bias0, const float* __restrict__ bias1,
    uint16_t* __restrict__ outb, float* __restrict__ partial)
{
  __shared__ unsigned char smem[32768];
  uint16_t* lA = (uint16_t*)smem;            // 128x64 bf16 = 16 KB
  uint16_t* lW = (uint16_t*)(smem + 16384);  // 128x64 bf16 = 16 KB

  const int tid = threadIdx.x;
  const int mb = blockIdx.x, nb = blockIdx.y;
  const int m0 = mb * 128, n0 = nb * 128;

  const uint16_t* Wp = W0;
  const float* biasp = bias0;
  int nr0 = n0;
  if (MODE == 0 && n0 >= 512) { Wp = W1; biasp = bias1; nr0 = n0 - 512; }

  const int w = tid >> 6, lane = tid & 63;
  const int mw = w & 1, nw = w >> 1;

  v4f acc[4][4];
#pragma unroll
  for (int i = 0; i < 4; ++i)
#pragma unroll
    for (int j = 0; j < 4; ++j) {
      v4f z = {0.f, 0.f, 0.f, 0.f};
      acc[i][j] = z;
    }

  const int r_st = tid >> 3;   // + p*32
  const int u_st = tid & 7;

  for (int kk = 0; kk < K; kk += 64) {
    __syncthreads();
#pragma unroll
    for (int p = 0; p < 4; ++p) {
      const int r = p * 32 + r_st;
      gl_lds16(A + (size_t)(m0 + r) * lda + kk + u_st * 8, lA + (p * 256 + tid) * 8);
    }
#pragma unroll
    for (int p = 0; p < 4; ++p) {
      const int r = p * 32 + r_st;
      gl_lds16(Wp + (size_t)(nr0 + r) * K + kk + u_st * 8, lW + (p * 256 + tid) * 8);
    }
    __syncthreads();
#pragma unroll
    for (int ks = 0; ks < 2; ++ks) {
      v8s af[4], wf[4];
#pragma unroll
      for (int i = 0; i < 4; ++i)
        af[i] = *(const v8s*)&lA[(mw * 64 + i * 16 + (lane & 15)) * 64 + ks * 32 + (lane >> 4) * 8];
#pragma unroll
      for (int j = 0; j < 4; ++j)
        wf[j] = *(const v8s*)&lW[(nw * 64 + j * 16 + (lane & 15)) * 64 + ks * 32 + (lane >> 4) * 8];
#pragma unroll
      for (int i = 0; i < 4; ++i)
#pragma unroll
        for (int j = 0; j < 4; ++j)
          acc[i][j] = __builtin_amdgcn_mfma_f32_16x16x32_bf16(af[i], wf[j], acc[i][j], 0, 0, 0);
    }
  }

  __syncthreads();  // all LDS frag reads done before epilogue reuse

  if (MODE == 0) {
#pragma unroll
    for (int i = 0; i < 4; ++i)
#pragma unroll
      for (int j = 0; j < 4; ++j) {
        const int nl = nw * 64 + j * 16 + (lane & 15);
        const float bv = biasp[nr0 + nl];
        const int colg = n0 + nl;
#pragma unroll
        for (int r = 0; r < 4; ++r) {
          const int rowg = m0 + mw * 64 + i * 16 + (lane >> 4) * 4 + r;
          outb[(size_t)rowg * 1024 + colg] = f2bf(acc[i][j][r] + bv);
        }
      }
  } else {
    float* lred = (float*)smem;   // 64 b x 128 n f32 = 32 KB
    if (mw == 1) {
#pragma unroll
      for (int i = 0; i < 4; ++i)
#pragma unroll
        for (int j = 0; j < 4; ++j) {
          const int nl = nw * 64 + j * 16 + (lane & 15);
          const float bv = biasp[nr0 + nl];
#pragma unroll
          for (int r = 0; r < 4; ++r) {
            const int bl = i * 16 + (lane >> 4) * 4 + r;
            lred[bl * 128 + nl] = tanhf(acc[i][j][r] + bv);
          }
        }
    }
    __syncthreads();
    if (mw == 0) {
#pragma unroll
      for (int i = 0; i < 4; ++i)
#pragma unroll
        for (int j = 0; j < 4; ++j) {
          const int nl = nw * 64 + j * 16 + (lane & 15);
          const float bv = biasp[nr0 + nl];
#pragma unroll
          for (int r = 0; r < 4; ++r) {
            const int bl = i * 16 + (lane >> 4) * 4 + r;
            const float v = tanhf(acc[i][j][r] + bv);
            partial[((size_t)mb * 64 + bl) * 1024 + n0 + nl] = fmaxf(v, lred[bl * 128 + nl]);
          }
        }
    }
  }
}

// ---------- K2: bidirectional recurrence, W-in-LDS + u64 seq-payload exchange ----------
// 256 blocks x 512 threads: block = (batch-pair pb 0..31, dir d, h-quarter qh 0..3).
// W quarter (128 h x 512 k bf16) in LDS (R4-validated). Exchange: each published
// c-pair is one RELAXED agent-scope u64 atomic {seq<<32 | payload} -> detection IS
// the gather (single L3 round trip; no flags, no release fences, no drain barrier).
// Parity double-buffer; lockstep argument bounds skew to 1 iter. Lanes 128-511
// poll-gather partner quarters WHILE lanes 0-127 finalize+publish. cat stores are
// software-pipelined to the next iteration top (off the barrier vmcnt drain).
__global__ __launch_bounds__(512) void scan_kernel(
    const uint16_t* __restrict__ ee,     // [32768][1024] bf16: ls | rs
    const uint16_t* __restrict__ wlb, const uint16_t* __restrict__ wrb,
    const float* __restrict__ bl, const float* __restrict__ br,
    const float* __restrict__ cl0, const float* __restrict__ cr0,
    uint16_t* __restrict__ cat,
    uint64_t* __restrict__ cbuf)
{
  const int tid = threadIdx.x;
  const int bid = blockIdx.x;
  const int qh = bid >> 6;          // h-quarter 0..3 (partners differ by 64 -> same bid%8)
  const int pb = (bid >> 1) & 31;   // batch pair
  const int d  = bid & 1;
  const int b0 = pb * 2;

  const int h2 = tid & 127;         // row within quarter
  const int kq = tid >> 7;          // 0..3: k-window of 128

  // W rows padded to 260 u32 (stride 1040 B -> lane bank-stride 4)
  __shared__ uint32_t wlds[128 * 260];   // 133120 B
  __shared__ uint32_t cpair[2 * 256];    // c per batch as 256 bf16-pairs
  __shared__ float    part[2 * 128 * 4]; // [b2][h2][kq] partial sums

  // ---- stage W quarter into LDS ----
  {
    const uint16_t* wsrc = (d ? wrb : wlb) + (size_t)(qh * 128 + h2) * HIDD + kq * 128;
    uint32_t* dstrow = &wlds[h2 * 260 + kq * 64];
#pragma unroll
    for (int j = 0; j < 16; ++j) {
      uint4 q = ((const uint4*)wsrc)[j];
      *(uint4*)(dstrow + j * 4) = q;
    }
  }
  // init c for both batches (same init vector)
  {
    const int b2 = tid >> 8, idx = tid & 255;
    const float* c0v = d ? cr0 : cl0;
    float2 cv = ((const float2*)c0v)[idx];
    cpair[b2 * 256 + idx] = pk2(cv.x, cv.y);
  }
  float2 biasv = {0.f, 0.f};
  if (tid < 128) {
    const float* bvec = d ? br : bl;
    biasv = ((const float2*)bvec)[qh * 64 + (tid & 63)];
  }
  __syncthreads();

  // finalize-thread geometry: b2 = tid>>6, p = tid&63 -> h pair (2p, 2p+1) of quarter
  const int fb2 = tid >> 6;
  const int fp  = tid & 63;
  const size_t ecol = (size_t)(d * 512 + qh * 128 + 2 * fp);
  const int fcol = (d ? 1024 : 0) + qh * 128 + 2 * fp;   // cat column for finalize lanes

  // gather-lane geometry (tid >= 128): partner pi 0..2, word j 0..127
  const int g  = tid - 128;
  const int pi = g >> 7;
  const int gj = g & 127;
  const int pq = (qh + 1 + pi) & 3;
  const int pbid = (pq << 6) | (pb << 1) | d;

  // 2-deep ee prefetch ring
  uint32_t ep0 = 0, ep1 = 0;
  if (tid < 128) {
    const int s0i = d ? 511 : 0;
    const int s1i = d ? 510 : 1;
    ep0 = *(const uint32_t*)&ee[(size_t)(s0i * BB + b0 + fb2) * 1024 + ecol];
    ep1 = *(const uint32_t*)&ee[(size_t)(s1i * BB + b0 + fb2) * 1024 + ecol];
  }

  uint32_t prPrev = 0;
  int sPrev = -1;

  for (int i = 0; i < 512; ++i) {
    const int s = d ? (511 - i) : i;
    uint32_t ep2 = 0;
    if (tid < 128) {
      const int i2 = (i + 2) & 511;
      const int s2 = d ? (511 - i2) : i2;
      ep2 = *(const uint32_t*)&ee[(size_t)(s2 * BB + b0 + fb2) * 1024 + ecol];
      // pipelined cat store from previous iteration (drains during the dot)
      if (sPrev >= 0)
        *(uint32_t*)&cat[(size_t)(sPrev * BB + b0 + fb2) * KCAT + fcol] = prPrev;
    }

    // dot: row h2, k-window [kq*128,+128), both batches. W per-lane b128; c broadcast.
    {
      const uint32_t* wr_ = &wlds[h2 * 260 + kq * 64];
      const uint32_t* ca_ = &cpair[kq * 64];
      const uint32_t* cb_ = &cpair[256 + kq * 64];
      float a00 = 0.f, a01 = 0.f, a10 = 0.f, a11 = 0.f;
#pragma unroll
      for (int j = 0; j < 16; ++j) {
        uint4 w4 = *(const uint4*)(wr_ + j * 4);
        uint4 c4 = *(const uint4*)(ca_ + j * 4);
        uint4 d4 = *(const uint4*)(cb_ + j * 4);
        a00 = dot2bf(w4.x, c4.x, a00); a01 = dot2bf(w4.y, c4.y, a01);
        a00 = dot2bf(w4.z, c4.z, a00); a01 = dot2bf(w4.w, c4.w, a01);
        a10 = dot2bf(w4.x, d4.x, a10); a11 = dot2bf(w4.y, d4.y, a11);
        a10 = dot2bf(w4.z, d4.z, a10); a11 = dot2bf(w4.w, d4.w, a11);
      }
      part[(h2 << 2) + kq]       = a00 + a01;
      part[512 + (h2 << 2) + kq] = a10 + a11;
    }
    __syncthreads();

    if (tid < 128) {
      // finalize: one c-pair of one batch
      float4 q0 = *(const float4*)&part[fb2 * 512 + (2 * fp) * 4];
      float4 q1 = *(const float4*)&part[fb2 * 512 + (2 * fp + 1) * 4];
      float s0 = ((q0.x + q0.y) + (q0.z + q0.w)) + biasv.x + bf2f(ep0 & 0xffffu);
      float s1 = ((q1.x + q1.y) + (q1.z + q1.w)) + biasv.y + bf2f(ep0 >> 16);
      uint32_t pr = pk2(tanhf(s0), tanhf(s1));
      cpair[fb2 * 256 + qh * 64 + fp] = pr;
      if (i != 511) {
        uint64_t pkt = ((uint64_t)(uint32_t)(i + 1) << 32) | (uint64_t)pr;
        __hip_atomic_store(&cbuf[(size_t)(((i & 1) * 256 + bid) * 128 + tid)],
                           pkt, __ATOMIC_RELAXED, __HIP_MEMORY_SCOPE_AGENT);
        prPrev = pr; sPrev = s;
      } else {
        // last step: store directly (no more iterations to pipeline into)
        *(uint32_t*)&cat[(size_t)(s * BB + b0 + fb2) * KCAT + fcol] = pr;
      }
    } else if (i != 511) {
      // poll-gather one partner word; seq embedded in the u64 -> single round trip
      const uint64_t want = (uint64_t)(uint32_t)(i + 1);
      const uint64_t* slot = &cbuf[(size_t)(((i & 1) * 256 + pbid) * 128 + gj)];
      uint64_t v = __hip_atomic_load(slot, __ATOMIC_RELAXED, __HIP_MEMORY_SCOPE_AGENT);
      while ((v >> 32) != want) {
        __builtin_amdgcn_s_sleep(1);
        v = __hip_atomic_load(slot, __ATOMIC_RELAXED, __HIP_MEMORY_SCOPE_AGENT);
      }
      cpair[(gj >> 6) * 256 + pq * 64 + (gj & 63)] = (uint32_t)v;
    }

    if (i == 511) break;
    __syncthreads();

    ep0 = ep1; ep1 = ep2;
  }
}

// ---------- K4: max-reduce partials, classifier, log_softmax ----------
__global__ __launch_bounds__(256) void final_kernel(
    const float* __restrict__ partial, const float* __restrict__ Wdoc,
    const float* __restrict__ bdoc, float* __restrict__ out)
{
  const int b = blockIdx.x, t = threadIdx.x;
  __shared__ float ym[1024];
  __shared__ float lg[32];
  float m0 = -2.f, m1 = -2.f, m2 = -2.f, m3 = -2.f;
  for (int mg = 0; mg < 256; ++mg) {
    const float* p = partial + ((size_t)mg * 64 + b) * 1024;
    m0 = fmaxf(m0, p[t]);
    m1 = fmaxf(m1, p[t + 256]);
    m2 = fmaxf(m2, p[t + 512]);
    m3 = fmaxf(m3, p[t + 768]);
  }
  ym[t] = m0; ym[t + 256] = m1; ym[t + 512] = m2; ym[t + 768] = m3;
  __syncthreads();
  if (t < NCLS) {
    const float* wr = Wdoc + (size_t)t * 1024;
    float a0 = 0.f, a1 = 0.f, a2 = 0.f, a3 = 0.f;
    for (int n = 0; n < 1024; n += 4) {
      a0 = fmaf(ym[n], wr[n], a0);
      a1 = fmaf(ym[n + 1], wr[n + 1], a1);
      a2 = fmaf(ym[n + 2], wr[n + 2], a2);
      a3 = fmaf(ym[n + 3], wr[n + 3], a3);
    }
    lg[t] = (a0 + a1) + (a2 + a3) + bdoc[t];
  }
  __syncthreads();
  if (t < NCLS) {
    float mx = -1e30f;
    for (int c = 0; c < NCLS; ++c) mx = fmaxf(mx, lg[c]);
    float ssum = 0.f;
    for (int c = 0; c < NCLS; ++c) ssum += expf(lg[c] - mx);
    out[b * NCLS + t] = lg[t] - mx - logf(ssum);
  }
}

// ---------- launch ----------
extern "C" void kernel_launch(void* const* d_in, const int* in_sizes, int n_in,
                              void* d_out, int out_size, void* d_ws, size_t ws_size,
                              hipStream_t stream) {
  const int*   inp   = (const int*)  d_in[0];
  const float* table = (const float*)d_in[1];
  const float* cl0   = (const float*)d_in[2];
  const float* cr0   = (const float*)d_in[3];
  const float* Wl    = (const float*)d_in[4];
  const float* bl    = (const float*)d_in[5];
  const float* Wr    = (const float*)d_in[6];
  const float* br    = (const float*)d_in[7];
  const float* Wsl   = (const float*)d_in[8];
  const float* bsl   = (const float*)d_in[9];
  const float* Wsr   = (const float*)d_in[10];
  const float* bsr   = (const float*)d_in[11];
  const float* Wmax  = (const float*)d_in[12];
  const float* bmax  = (const float*)d_in[13];
  const float* Wdoc  = (const float*)d_in[14];
  const float* bdoc  = (const float*)d_in[15];

  uint8_t* ws = (uint8_t*)d_ws;
  uint16_t* cat     = (uint16_t*)(ws);                 // 32768*1536*2 = 100663296
  uint16_t* ee      = (uint16_t*)(ws + 100663296);     // 32768*1024*2 = 67108864
  float*    partial = (float*)   (ws + 167772160);     // 256*64*1024*4 = 67108864
  uint16_t* wslb    = (uint16_t*)(ws + 234881024);     // 524288
  uint16_t* wsrb    = (uint16_t*)(ws + 235405312);     // 524288
  uint16_t* wmaxb   = (uint16_t*)(ws + 235929600);     // 3145728
  uint16_t* wlb     = (uint16_t*)(ws + 239075328);     // 524288
  uint16_t* wrb     = (uint16_t*)(ws + 239599616);     // 524288
  // cbuf (u64 seq|payload, 2 parity x 256 bid x 128 words = 512 KB) overlays the
  // START of `partial`: poisoned 0xAA at launch (seq never matches), and gemm<1>
  // fully overwrites partial AFTER the scan completes. No ws growth.
  uint64_t* cbuf    = (uint64_t*)(ws + 167772160);

  prep_kernel<<<9472, 256, 0, stream>>>(inp, table, Wsl, Wsr, Wl, Wr, Wmax,
                                        cat, wslb, wsrb, wlb, wrb, wmaxb);
  gemm_kernel<0><<<dim3(256, 8), 256, 0, stream>>>(cat + 512, KCAT, 512, wslb, wsrb,
                                                   bsl, bsr, ee, nullptr);
  scan_kernel<<<256, 512, 0, stream>>>(ee, wlb, wrb, bl, br, cl0, cr0, cat, cbuf);
  gemm_kernel<1><<<dim3(256, 8), 256, 0, stream>>>(cat, KCAT, KCAT, wmaxb, nullptr,
                                                   bmax, nullptr, nullptr, partial);
  final_kernel<<<64, 256, 0, stream>>>(partial, Wdoc, bdoc, (float*)d_out);
}